// Round 5
// baseline (443.198 us; speedup 1.0000x reference)
//
#include <hip/hip_runtime.h>
#include <cstdint>
#include <cstddef>

// ---------------------------------------------------------------------------
// MSA: out = proj(softmax(Q K^T * scale) V) for B=4, N=2048, C=1024, H=16, HD=64
// bf16/f16 MFMA pipeline:
//   1. convert x -> bf16                       [8192,1024]
//   2. transpose-convert w_qkv -> bf16 [3072,1024], w_proj -> bf16 [1024,1024]
//   3. GEMM qkv (128x128 tile, global_load_lds): scatter Q*(scale*log2e), K ->
//      [BH,2048,64] bf16, V -> transposed [BH,64,2048] **f16** (pkrtz)
//   4. attention: 128 q/block (32/wave), BKV=64, S^T=K·Q^T, no-max softmax,
//      p=exp2(s) packed to f16 via v_cvt_pkrtz, PV in f16 MFMA,
//      V frags loaded global->VGPR directly (precise scoreboard),
//      K-only LDS double-buffer with barrier-first prefetch (1 barrier/tile),
//      LDS 32.7KB -> 4 blocks/CU resident (grid = 4 blocks/CU exactly)
//   5. GEMM proj + bias -> fp32 d_out
// ---------------------------------------------------------------------------

typedef __attribute__((ext_vector_type(8))) short short8;   // 8 x bf16 (4 VGPRs)
typedef __attribute__((ext_vector_type(4))) float f32x4;    // MFMA C/D
typedef _Float16 half8 __attribute__((ext_vector_type(8)));

#if __has_builtin(__builtin_amdgcn_exp2f)
#define EXP2F(x) __builtin_amdgcn_exp2f(x)
#else
#define EXP2F(x) __expf((x) * 0.69314718056f)
#endif

__device__ __forceinline__ short f2bf(float x) {            // RNE float->bf16 bits
  unsigned u = __builtin_bit_cast(unsigned, x);
  u += 0x7fffu + ((u >> 16) & 1u);
  return (short)(u >> 16);
}

__device__ __forceinline__ unsigned pkh(float a, float b) { // pack 2xf32 -> f16x2
  auto h = __builtin_amdgcn_cvt_pkrtz(a, b);                // __fp16 ext_vector(2)
  return __builtin_bit_cast(unsigned, h);
}

__device__ __forceinline__ void async16(const void* g, void* l) {
  // 16B per lane, LDS dest = wave-uniform base + lane*16
  __builtin_amdgcn_global_load_lds(
      (const __attribute__((address_space(1))) unsigned*)g,
      (__attribute__((address_space(3))) unsigned*)l, 16, 0, 0);
}

// ------------------------------- casts -------------------------------------

__global__ __launch_bounds__(256) void convert_kernel(const float* __restrict__ in,
                                                      short* __restrict__ out) {
  int i = blockIdx.x * 256 + threadIdx.x;          // 8 elems/thread
  const float4* p = (const float4*)in + (size_t)i * 2;
  float4 a = p[0], b = p[1];
  short8 r;
  r[0] = f2bf(a.x); r[1] = f2bf(a.y); r[2] = f2bf(a.z); r[3] = f2bf(a.w);
  r[4] = f2bf(b.x); r[5] = f2bf(b.y); r[6] = f2bf(b.z); r[7] = f2bf(b.w);
  *((short8*)out + i) = r;
}

// in: fp32 [K,N] row-major  ->  out: bf16 [N,K] row-major
__global__ __launch_bounds__(256) void wtrans_kernel(const float* __restrict__ in,
                                                     short* __restrict__ out,
                                                     int K, int N) {
  __shared__ float tile[32][33];
  int n0 = blockIdx.x * 32, k0 = blockIdx.y * 32;
  int tx = threadIdx.x, ty = threadIdx.y;          // block (32,8)
  for (int r = ty; r < 32; r += 8)
    tile[r][tx] = in[(size_t)(k0 + r) * N + n0 + tx];
  __syncthreads();
  for (int r = ty; r < 32; r += 8)
    out[(size_t)(n0 + r) * K + k0 + tx] = f2bf(tile[tx][r]);
}

// ------------------------------- GEMM --------------------------------------
// C[M,Nn] = A[M,1024] * Bt[Nn,1024]^T ; 128x128 block tile, BK=32, 4 waves,
// each wave 64x64 (4x4 of 16x16x32 MFMA).
// MODE 0: QKV epilogue (bias, scale Q by SCALE*log2e, scatter q/k bf16, vT f16)
// MODE 1: proj epilogue (bias, fp32 out)

template <int MODE>
__global__ __launch_bounds__(256) void gemm_kernel(
    const short* __restrict__ A, const short* __restrict__ Bt,
    const float* __restrict__ bias, int Nn,
    short* __restrict__ qb, short* __restrict__ kb, short* __restrict__ vtb,
    float* __restrict__ outp) {
  constexpr int K = 1024;
  __shared__ __align__(16) short As[128 * 32];
  __shared__ __align__(16) short Bs[128 * 32];
  const int tid = threadIdx.x, wave = tid >> 6, lane = tid & 63;
  const int quad = lane >> 4, l16 = lane & 15;
  const int m0 = blockIdx.y * 128, n0 = blockIdx.x * 128;
  const int wrow = (wave >> 1) * 64, wcol = (wave & 1) * 64;

  const int str = lane >> 2;
  const int sgc = ((lane & 3) ^ ((lane >> 3) & 3)) * 8;   // shorts
  const short* Ag = A + (size_t)(m0 + str) * K + sgc;
  const short* Bg = Bt + (size_t)(n0 + str) * K + sgc;

  const int fsw = (l16 >> 1) & 3;

  f32x4 acc[4][4] = {};

  for (int k0 = 0; k0 < K; k0 += 32) {
#pragma unroll
    for (int i = 0; i < 2; ++i) {
      int c = wave * 2 + i;
      async16(Ag + (size_t)c * 16 * K + k0, (char*)As + c * 1024);
      async16(Bg + (size_t)c * 16 * K + k0, (char*)Bs + c * 1024);
    }
    __syncthreads();
    short8 af[4], bf[4];
#pragma unroll
    for (int t = 0; t < 4; ++t) {
      af[t] = *(const short8*)&As[(wrow + t * 16 + l16) * 32 + ((quad ^ fsw) << 3)];
      bf[t] = *(const short8*)&Bs[(wcol + t * 16 + l16) * 32 + ((quad ^ fsw) << 3)];
    }
#pragma unroll
    for (int mt = 0; mt < 4; ++mt)
#pragma unroll
      for (int nt = 0; nt < 4; ++nt)
        acc[mt][nt] = __builtin_amdgcn_mfma_f32_16x16x32_bf16(af[mt], bf[nt],
                                                              acc[mt][nt], 0, 0, 0);
    __syncthreads();
  }

  // epilogue: C/D layout col = l16, row = quad*4 + reg
  if (MODE == 0) {
#pragma unroll
    for (int mt = 0; mt < 4; ++mt) {
      int row0 = m0 + wrow + mt * 16 + quad * 4;
      int b = row0 >> 11, n = row0 & 2047;
#pragma unroll
      for (int nt = 0; nt < 4; ++nt) {
        int col = n0 + wcol + nt * 16 + l16;
        float bv = bias[col];
        float v0 = acc[mt][nt][0] + bv, v1 = acc[mt][nt][1] + bv;
        float v2 = acc[mt][nt][2] + bv, v3 = acc[mt][nt][3] + bv;
        int which = col >> 10;
        int h = (col >> 6) & 15;
        int d = col & 63;
        size_t bh = (size_t)(b * 16 + h);
        if (which == 0) {             // Q, pre-scaled by SCALE*log2(e)
          const float qs = 0.18033688f;   // 0.125 * 1.44269504
          size_t base = (bh * 2048 + n) * 64 + d;
          qb[base]       = f2bf(v0 * qs);
          qb[base + 64]  = f2bf(v1 * qs);
          qb[base + 128] = f2bf(v2 * qs);
          qb[base + 192] = f2bf(v3 * qs);
        } else if (which == 1) {      // K
          size_t base = (bh * 2048 + n) * 64 + d;
          kb[base]       = f2bf(v0);
          kb[base + 64]  = f2bf(v1);
          kb[base + 128] = f2bf(v2);
          kb[base + 192] = f2bf(v3);
        } else {                      // V transposed: [bh, d, n] f16, 4 tokens
          uint2 pk;
          pk.x = pkh(v0, v1);
          pk.y = pkh(v2, v3);
          *(uint2*)&vtb[(bh * 64 + d) * 2048 + n] = pk;
        }
      }
    }
  } else {
#pragma unroll
    for (int mt = 0; mt < 4; ++mt) {
      int row0 = m0 + wrow + mt * 16 + quad * 4;
#pragma unroll
      for (int nt = 0; nt < 4; ++nt) {
        int col = n0 + wcol + nt * 16 + l16;
        float bv = bias[col];
        outp[(size_t)row0 * Nn + col]       = acc[mt][nt][0] + bv;
        outp[(size_t)(row0 + 1) * Nn + col] = acc[mt][nt][1] + bv;
        outp[(size_t)(row0 + 2) * Nn + col] = acc[mt][nt][2] + bv;
        outp[(size_t)(row0 + 3) * Nn + col] = acc[mt][nt][3] + bv;
      }
    }
  }
}

// ----------------------------- attention -----------------------------------
// One block = one (b,h) x 128 q-rows; 4 waves, 32 q-rows each. BKV = 64.
// Q pre-scaled by SCALE*log2e. qb/kb: [BH,2048,64] bf16; vtb: [BH,64,2048] f16.
// S^T = K Q^T (A=K m=kv, B=Q n=q): lane holds q = qt*16+l16, kv = kvt*16+quad*4+r.
// No-max softmax: p = exp2(s) packed f16 via v_cvt_pkrtz; per-lane l partials
// reduced once at the end. K: LDS dbuf, barrier-first prefetch (1 barrier/tile).
// V: direct global->VGPR frags (precise scoreboard; K prefetch stays in flight).
// ob: [B, 2048, 1024] bf16 attention output.

__global__ __launch_bounds__(256, 4) void attn_kernel(
    const short* __restrict__ qb, const short* __restrict__ kb,
    const short* __restrict__ vtb, short* __restrict__ ob) {
  __shared__ __align__(16) short Ks[2][64 * 64];
  __shared__ __align__(16) short Ps[4][32 * 64];  // per-wave [q_local][kv], f16
  __shared__ __align__(16) float Ls[4][32];
  const int tid = threadIdx.x, wave = tid >> 6, lane = tid & 63;
  const int quad = lane >> 4, l16 = lane & 15;
  const int q0 = blockIdx.x * 128;
  const int bh = blockIdx.y;
  const short* Qg = qb + (size_t)bh * (2048 * 64);
  const short* Kg = kb + (size_t)bh * (2048 * 64);
  const _Float16* Vg = (const _Float16*)(vtb + (size_t)bh * (64 * 2048));

  // Q fragments: global -> registers once; B-operand layout
  short8 qf[2][2];
#pragma unroll
  for (int qt = 0; qt < 2; ++qt)
#pragma unroll
    for (int kc = 0; kc < 2; ++kc)
      qf[qt][kc] = *(const short8*)
          &Qg[(size_t)(q0 + wave * 32 + qt * 16 + l16) * 64 + kc * 32 + quad * 8];

  const int str = lane >> 3;
  const int sgc = ((lane & 7) ^ (str & 7)) * 8;   // chunk-of-8 swizzle (shorts)
  const int fsw = l16 & 7;
  short* Pw = Ps[wave];
  const int c0 = wave * 2, c1 = wave * 2 + 1;

  // prologue: stage K tile 0 into buffer 0
  async16(Kg + (size_t)(c0 * 8 + str) * 64 + sgc, (char*)Ks[0] + c0 * 1024);
  async16(Kg + (size_t)(c1 * 8 + str) * 64 + sgc, (char*)Ks[0] + c1 * 1024);

  float lsum[2] = {0.f, 0.f};
  f32x4 oacc[2][4] = {};   // [qt][nt]: q = qt*16+quad*4+r, d = nt*16+l16

  for (int t = 0; t < 32; ++t) {
    // barrier FIRST: drains K[t] (issued last iter / prologue, had a full
    // compute phase to land) and protects Ks buffer reuse across waves.
    __syncthreads();

    int kvn = (t + 1) * 64;
    if (kvn < 2048) {
      char* kd = (char*)Ks[(t + 1) & 1];
      async16(Kg + (size_t)(kvn + c0 * 8 + str) * 64 + sgc, kd + c0 * 1024);
      async16(Kg + (size_t)(kvn + c1 * 8 + str) * 64 + sgc, kd + c1 * 1024);
    }
    const short* Kst = Ks[t & 1];
    const int kv0 = t * 64;

    // S^T = K Q^T
    f32x4 sacc[2][4] = {};   // [qt][kvt]
#pragma unroll
    for (int kc = 0; kc < 2; ++kc) {
      short8 kf[4];
#pragma unroll
      for (int kvt = 0; kvt < 4; ++kvt)
        kf[kvt] = *(const short8*)
            &Kst[(kvt * 16 + l16) * 64 + (((kc * 4 + quad) ^ fsw) << 3)];
#pragma unroll
      for (int kvt = 0; kvt < 4; ++kvt)
#pragma unroll
        for (int qt = 0; qt < 2; ++qt)
          sacc[qt][kvt] = __builtin_amdgcn_mfma_f32_16x16x32_bf16(
              kf[kvt], qf[qt][kc], sacc[qt][kvt], 0, 0, 0);
    }

    // V fragments for this tile: direct global->VGPR (B-operand f16 layout);
    // latency overlaps the exp/pack phase below (precise per-reg scoreboard).
    half8 vf[2][4];
#pragma unroll
    for (int kc = 0; kc < 2; ++kc)
#pragma unroll
      for (int nt = 0; nt < 4; ++nt)
        vf[kc][nt] = *(const half8*)
            &Vg[(size_t)(nt * 16 + l16) * 2048 + kv0 + kc * 32 + quad * 8];

    // p = exp2(s); pack 4 consecutive kv -> one b64 LDS write (f16 pkrtz)
#pragma unroll
    for (int qt = 0; qt < 2; ++qt)
#pragma unroll
      for (int kvt = 0; kvt < 4; ++kvt) {
        float p0 = EXP2F(sacc[qt][kvt][0]);
        float p1 = EXP2F(sacc[qt][kvt][1]);
        float p2 = EXP2F(sacc[qt][kvt][2]);
        float p3 = EXP2F(sacc[qt][kvt][3]);
        lsum[qt] += (p0 + p1) + (p2 + p3);
        uint2 w;
        w.x = pkh(p0, p1);
        w.y = pkh(p2, p3);
        // kv base = kvt*16 + quad*4: chunk idx = kvt*2+(quad>>1), sub (quad&1)*4
        *(uint2*)&Pw[(qt * 16 + l16) * 64 +
                     ((((kvt * 2 + (quad >> 1)) ^ fsw)) << 3) + (quad & 1) * 4] = w;
      }

    __asm__ volatile("s_waitcnt lgkmcnt(0)" ::: "memory");

    // O += P V  (A=P m=q f16, B=V n=d f16)
#pragma unroll
    for (int kc = 0; kc < 2; ++kc) {
      half8 pf[2];
#pragma unroll
      for (int qt = 0; qt < 2; ++qt)
        pf[qt] = __builtin_bit_cast(half8, *(const short8*)
            &Pw[(qt * 16 + l16) * 64 + (((kc * 4 + quad) ^ fsw) << 3)]);
#pragma unroll
      for (int qt = 0; qt < 2; ++qt)
#pragma unroll
        for (int nt = 0; nt < 4; ++nt)
          oacc[qt][nt] = __builtin_amdgcn_mfma_f32_16x16x32_f16(
              pf[qt], vf[kc][nt], oacc[qt][nt], 0, 0, 0);
    }
    // no trailing barrier: next iteration's leading barrier covers reuse.
  }

  // final l reduction: lane has partial for q = qt*16+l16 over its quad's kv cols
#pragma unroll
  for (int qt = 0; qt < 2; ++qt) {
    float v = lsum[qt];
    v += __shfl_xor(v, 16, 64);
    v += __shfl_xor(v, 32, 64);
    if (quad == 0) Ls[wave][qt * 16 + l16] = v;
  }
  __asm__ volatile("s_waitcnt lgkmcnt(0)" ::: "memory");

  const int b = bh >> 4, h = bh & 15;
#pragma unroll
  for (int qt = 0; qt < 2; ++qt) {
    float4 lr = *(const float4*)&Ls[wave][qt * 16 + quad * 4];
    float inv0 = 1.f / lr.x, inv1 = 1.f / lr.y, inv2 = 1.f / lr.z, inv3 = 1.f / lr.w;
#pragma unroll
    for (int nt = 0; nt < 4; ++nt) {
      int d = nt * 16 + l16;
      int qbase = q0 + wave * 32 + qt * 16 + quad * 4;
      size_t obase = ((size_t)(b * 2048 + qbase)) * 1024 + h * 64 + d;
      ob[obase]        = f2bf(oacc[qt][nt][0] * inv0);
      ob[obase + 1024] = f2bf(oacc[qt][nt][1] * inv1);
      ob[obase + 2048] = f2bf(oacc[qt][nt][2] * inv2);
      ob[obase + 3072] = f2bf(oacc[qt][nt][3] * inv3);
    }
  }
}

// ----------------------------- launch --------------------------------------

extern "C" void kernel_launch(void* const* d_in, const int* in_sizes, int n_in,
                              void* d_out, int out_size, void* d_ws, size_t ws_size,
                              hipStream_t stream) {
  const float* x      = (const float*)d_in[0];
  const float* w_qkv  = (const float*)d_in[1];
  const float* b_qkv  = (const float*)d_in[2];
  const float* w_proj = (const float*)d_in[3];
  const float* b_proj = (const float*)d_in[4];
  float* out = (float*)d_out;

  short* xs     = (short*)d_ws;                     // [8192,1024]
  short* wqkvT  = xs + (size_t)8192 * 1024;         // [3072,1024]
  short* wprojT = wqkvT + (size_t)3072 * 1024;      // [1024,1024]
  short* qb     = wprojT + (size_t)1024 * 1024;     // [64,2048,64]
  short* kb     = qb + (size_t)64 * 2048 * 64;      // [64,2048,64]
  short* vtb    = kb + (size_t)64 * 2048 * 64;      // [64,64,2048] f16
  short* aob    = vtb + (size_t)64 * 2048 * 64;     // [8192,1024]

  convert_kernel<<<dim3(4096), 256, 0, stream>>>(x, xs);
  wtrans_kernel<<<dim3(96, 32), dim3(32, 8), 0, stream>>>(w_qkv, wqkvT, 1024, 3072);
  wtrans_kernel<<<dim3(32, 32), dim3(32, 8), 0, stream>>>(w_proj, wprojT, 1024, 1024);

  gemm_kernel<0><<<dim3(24, 64), 256, 0, stream>>>(xs, wqkvT, b_qkv, 3072,
                                                   qb, kb, vtb, nullptr);
  attn_kernel<<<dim3(16, 64), 256, 0, stream>>>(qb, kb, vtb, aob);
  gemm_kernel<1><<<dim3(8, 64), 256, 0, stream>>>(aob, wprojT, b_proj, 1024,
                                                  nullptr, nullptr, nullptr, out);
}

// Round 6
// 282.819 us; speedup vs baseline: 1.5671x; 1.5671x over previous
//
#include <hip/hip_runtime.h>
#include <cstdint>
#include <cstddef>

// ---------------------------------------------------------------------------
// MSA: out = proj(softmax(Q K^T * scale) V) for B=4, N=2048, C=1024, H=16, HD=64
// bf16/f16 MFMA pipeline:
//   1. convert x -> bf16                       [8192,1024]
//   2. transpose-convert w_qkv -> bf16 [3072,1024], w_proj -> bf16 [1024,1024]
//   3. GEMM qkv (128x128 tile, global_load_lds): scatter Q*(scale*log2e), K ->
//      [BH,2048,64] bf16, V -> transposed [BH,64,2048] f16 (pkrtz)
//   4. attention: 128 q/block (32/wave), BKV=64, S^T=K·Q^T, no-max softmax,
//      p=exp2(s). KEY: S^T's C-layout (m=kv on quad*4+r, n=q on l16) equals the
//      A-layout of mfma_f32_16x16x16_f16 (m=l16, k=quad*4+j) -> P feeds PV
//      directly from registers (pkrtz pack only). No P LDS round-trip, no
//      bank conflicts, no lgkm drain. K+V both LDS double-buffered (32.2 KB,
//      4 blocks/CU), barrier-first prefetch, 1 barrier/tile.
//   5. GEMM proj + bias -> fp32 d_out
// ---------------------------------------------------------------------------

typedef __attribute__((ext_vector_type(8))) short short8;   // 8 x bf16 (4 VGPRs)
typedef __attribute__((ext_vector_type(4))) float f32x4;    // MFMA C/D
typedef _Float16 half4 __attribute__((ext_vector_type(4))); // 16x16x16 A/B frag

#if __has_builtin(__builtin_amdgcn_exp2f)
#define EXP2F(x) __builtin_amdgcn_exp2f(x)
#else
#define EXP2F(x) __expf((x) * 0.69314718056f)
#endif

__device__ __forceinline__ short f2bf(float x) {            // RNE float->bf16 bits
  unsigned u = __builtin_bit_cast(unsigned, x);
  u += 0x7fffu + ((u >> 16) & 1u);
  return (short)(u >> 16);
}

__device__ __forceinline__ unsigned pkh(float a, float b) { // pack 2xf32 -> f16x2
  auto h = __builtin_amdgcn_cvt_pkrtz(a, b);                // __fp16 ext_vector(2)
  return __builtin_bit_cast(unsigned, h);
}

__device__ __forceinline__ void async16(const void* g, void* l) {
  // 16B per lane, LDS dest = wave-uniform base + lane*16
  __builtin_amdgcn_global_load_lds(
      (const __attribute__((address_space(1))) unsigned*)g,
      (__attribute__((address_space(3))) unsigned*)l, 16, 0, 0);
}

// ------------------------------- casts -------------------------------------

__global__ __launch_bounds__(256) void convert_kernel(const float* __restrict__ in,
                                                      short* __restrict__ out) {
  int i = blockIdx.x * 256 + threadIdx.x;          // 8 elems/thread
  const float4* p = (const float4*)in + (size_t)i * 2;
  float4 a = p[0], b = p[1];
  short8 r;
  r[0] = f2bf(a.x); r[1] = f2bf(a.y); r[2] = f2bf(a.z); r[3] = f2bf(a.w);
  r[4] = f2bf(b.x); r[5] = f2bf(b.y); r[6] = f2bf(b.z); r[7] = f2bf(b.w);
  *((short8*)out + i) = r;
}

// in: fp32 [K,N] row-major  ->  out: bf16 [N,K] row-major
__global__ __launch_bounds__(256) void wtrans_kernel(const float* __restrict__ in,
                                                     short* __restrict__ out,
                                                     int K, int N) {
  __shared__ float tile[32][33];
  int n0 = blockIdx.x * 32, k0 = blockIdx.y * 32;
  int tx = threadIdx.x, ty = threadIdx.y;          // block (32,8)
  for (int r = ty; r < 32; r += 8)
    tile[r][tx] = in[(size_t)(k0 + r) * N + n0 + tx];
  __syncthreads();
  for (int r = ty; r < 32; r += 8)
    out[(size_t)(n0 + r) * K + k0 + tx] = f2bf(tile[tx][r]);
}

// ------------------------------- GEMM --------------------------------------
// C[M,Nn] = A[M,1024] * Bt[Nn,1024]^T ; 128x128 block tile, BK=32, 4 waves,
// each wave 64x64 (4x4 of 16x16x32 MFMA).
// MODE 0: QKV epilogue (bias, scale Q by SCALE*log2e, scatter q/k bf16, vT f16)
// MODE 1: proj epilogue (bias, fp32 out)

template <int MODE>
__global__ __launch_bounds__(256) void gemm_kernel(
    const short* __restrict__ A, const short* __restrict__ Bt,
    const float* __restrict__ bias, int Nn,
    short* __restrict__ qb, short* __restrict__ kb, short* __restrict__ vtb,
    float* __restrict__ outp) {
  constexpr int K = 1024;
  __shared__ __align__(16) short As[128 * 32];
  __shared__ __align__(16) short Bs[128 * 32];
  const int tid = threadIdx.x, wave = tid >> 6, lane = tid & 63;
  const int quad = lane >> 4, l16 = lane & 15;
  const int m0 = blockIdx.y * 128, n0 = blockIdx.x * 128;
  const int wrow = (wave >> 1) * 64, wcol = (wave & 1) * 64;

  const int str = lane >> 2;
  const int sgc = ((lane & 3) ^ ((lane >> 3) & 3)) * 8;   // shorts
  const short* Ag = A + (size_t)(m0 + str) * K + sgc;
  const short* Bg = Bt + (size_t)(n0 + str) * K + sgc;

  const int fsw = (l16 >> 1) & 3;

  f32x4 acc[4][4] = {};

  for (int k0 = 0; k0 < K; k0 += 32) {
#pragma unroll
    for (int i = 0; i < 2; ++i) {
      int c = wave * 2 + i;
      async16(Ag + (size_t)c * 16 * K + k0, (char*)As + c * 1024);
      async16(Bg + (size_t)c * 16 * K + k0, (char*)Bs + c * 1024);
    }
    __syncthreads();
    short8 af[4], bf[4];
#pragma unroll
    for (int t = 0; t < 4; ++t) {
      af[t] = *(const short8*)&As[(wrow + t * 16 + l16) * 32 + ((quad ^ fsw) << 3)];
      bf[t] = *(const short8*)&Bs[(wcol + t * 16 + l16) * 32 + ((quad ^ fsw) << 3)];
    }
#pragma unroll
    for (int mt = 0; mt < 4; ++mt)
#pragma unroll
      for (int nt = 0; nt < 4; ++nt)
        acc[mt][nt] = __builtin_amdgcn_mfma_f32_16x16x32_bf16(af[mt], bf[nt],
                                                              acc[mt][nt], 0, 0, 0);
    __syncthreads();
  }

  // epilogue: C/D layout col = l16, row = quad*4 + reg
  if (MODE == 0) {
#pragma unroll
    for (int mt = 0; mt < 4; ++mt) {
      int row0 = m0 + wrow + mt * 16 + quad * 4;
      int b = row0 >> 11, n = row0 & 2047;
#pragma unroll
      for (int nt = 0; nt < 4; ++nt) {
        int col = n0 + wcol + nt * 16 + l16;
        float bv = bias[col];
        float v0 = acc[mt][nt][0] + bv, v1 = acc[mt][nt][1] + bv;
        float v2 = acc[mt][nt][2] + bv, v3 = acc[mt][nt][3] + bv;
        int which = col >> 10;
        int h = (col >> 6) & 15;
        int d = col & 63;
        size_t bh = (size_t)(b * 16 + h);
        if (which == 0) {             // Q, pre-scaled by SCALE*log2(e)
          const float qs = 0.18033688f;   // 0.125 * 1.44269504
          size_t base = (bh * 2048 + n) * 64 + d;
          qb[base]       = f2bf(v0 * qs);
          qb[base + 64]  = f2bf(v1 * qs);
          qb[base + 128] = f2bf(v2 * qs);
          qb[base + 192] = f2bf(v3 * qs);
        } else if (which == 1) {      // K
          size_t base = (bh * 2048 + n) * 64 + d;
          kb[base]       = f2bf(v0);
          kb[base + 64]  = f2bf(v1);
          kb[base + 128] = f2bf(v2);
          kb[base + 192] = f2bf(v3);
        } else {                      // V transposed: [bh, d, n] f16, 4 tokens
          uint2 pk;
          pk.x = pkh(v0, v1);
          pk.y = pkh(v2, v3);
          *(uint2*)&vtb[(bh * 64 + d) * 2048 + n] = pk;
        }
      }
    }
  } else {
#pragma unroll
    for (int mt = 0; mt < 4; ++mt) {
      int row0 = m0 + wrow + mt * 16 + quad * 4;
#pragma unroll
      for (int nt = 0; nt < 4; ++nt) {
        int col = n0 + wcol + nt * 16 + l16;
        float bv = bias[col];
        outp[(size_t)row0 * Nn + col]       = acc[mt][nt][0] + bv;
        outp[(size_t)(row0 + 1) * Nn + col] = acc[mt][nt][1] + bv;
        outp[(size_t)(row0 + 2) * Nn + col] = acc[mt][nt][2] + bv;
        outp[(size_t)(row0 + 3) * Nn + col] = acc[mt][nt][3] + bv;
      }
    }
  }
}

// ----------------------------- attention -----------------------------------
// One block = one (b,h) x 128 q-rows; 4 waves, 32 q-rows each. BKV = 64.
// Q pre-scaled by SCALE*log2e. qb/kb: [BH,2048,64] bf16; vtb: [BH,64,2048] f16.
// S^T = K Q^T via 16x16x32 bf16 (A=K m=kv, B=Q n=q): lane holds
// q=qt*16+l16, kv=kvt*16+quad*4+r — which IS the A-layout of
// mfma_f32_16x16x16_f16 (m=l16, k=quad*4+j) for k-block kvt. So P goes
// exp2 -> pkrtz -> straight into PV MFMA from registers. V B-frags (n=d,
// k=quad*4+j consecutive kv) are ds_read_b64 from the swizzled Vs tile.
// K+V double-buffered, barrier-first prefetch, 1 barrier/tile, 4 blocks/CU.
// ob: [B, 2048, 1024] bf16 attention output.

__global__ __launch_bounds__(256, 4) void attn_kernel(
    const short* __restrict__ qb, const short* __restrict__ kb,
    const short* __restrict__ vtb, short* __restrict__ ob) {
  __shared__ __align__(16) short Ks[2][64 * 64];  // bf16 [kv][d]
  __shared__ __align__(16) short Vs[2][64 * 64];  // f16  [d][kv]
  __shared__ __align__(16) float Ls[4][32];
  const int tid = threadIdx.x, wave = tid >> 6, lane = tid & 63;
  const int quad = lane >> 4, l16 = lane & 15;
  const int q0 = blockIdx.x * 128;
  const int bh = blockIdx.y;
  const short* Qg = qb + (size_t)bh * (2048 * 64);
  const short* Kg = kb + (size_t)bh * (2048 * 64);
  const short* Vg = vtb + (size_t)bh * (64 * 2048);

  // Q fragments: global -> registers once; B-operand layout (n=q on l16,
  // k = kc*32 + quad*8 + j contiguous d)
  short8 qf[2][2];
#pragma unroll
  for (int qt = 0; qt < 2; ++qt)
#pragma unroll
    for (int kc = 0; kc < 2; ++kc)
      qf[qt][kc] = *(const short8*)
          &Qg[(size_t)(q0 + wave * 32 + qt * 16 + l16) * 64 + kc * 32 + quad * 8];

  const int str = lane >> 3;
  const int sgc = ((lane & 7) ^ (str & 7)) * 8;   // chunk-of-8 swizzle (shorts)
  const int fsw = l16 & 7;
  const int c0 = wave * 2, c1 = wave * 2 + 1;

  // prologue: stage K/V tile 0 into buffer 0
  async16(Kg + (size_t)(c0 * 8 + str) * 64 + sgc, (char*)Ks[0] + c0 * 1024);
  async16(Kg + (size_t)(c1 * 8 + str) * 64 + sgc, (char*)Ks[0] + c1 * 1024);
  async16(Vg + (size_t)(c0 * 8 + str) * 2048 + sgc, (char*)Vs[0] + c0 * 1024);
  async16(Vg + (size_t)(c1 * 8 + str) * 2048 + sgc, (char*)Vs[0] + c1 * 1024);

  float lsum[2] = {0.f, 0.f};
  f32x4 oacc[2][4] = {};   // [qt][nt]: q = qt*16+quad*4+r? no: C of PV has
                           // m=q on... PV: A=P(m=q), B=V(n=d) -> C col=l16=d?
                           // C/D: col(n=d)=l16, row(m=q)=quad*4+r. [qt][nt]

  for (int t = 0; t < 32; ++t) {
    // barrier FIRST: drains buf[t&1] loads (issued last iter / prologue,
    // overlapped with compute of t-1) and protects buffer reuse.
    __syncthreads();

    int kvn = (t + 1) * 64;
    if (kvn < 2048) {
      char* kd = (char*)Ks[(t + 1) & 1];
      char* vd = (char*)Vs[(t + 1) & 1];
      async16(Kg + (size_t)(kvn + c0 * 8 + str) * 64 + sgc, kd + c0 * 1024);
      async16(Kg + (size_t)(kvn + c1 * 8 + str) * 64 + sgc, kd + c1 * 1024);
      async16(Vg + (size_t)(c0 * 8 + str) * 2048 + kvn + sgc, vd + c0 * 1024);
      async16(Vg + (size_t)(c1 * 8 + str) * 2048 + kvn + sgc, vd + c1 * 1024);
    }
    const short* Kst = Ks[t & 1];
    const short* Vst = Vs[t & 1];

    // S^T = K Q^T  (16x16x32 bf16)
    f32x4 sacc[2][4] = {};   // [qt][kvt]
#pragma unroll
    for (int kc = 0; kc < 2; ++kc) {
      short8 kf[4];
#pragma unroll
      for (int kvt = 0; kvt < 4; ++kvt)
        kf[kvt] = *(const short8*)
            &Kst[(kvt * 16 + l16) * 64 + (((kc * 4 + quad) ^ fsw) << 3)];
#pragma unroll
      for (int kvt = 0; kvt < 4; ++kvt)
#pragma unroll
        for (int qt = 0; qt < 2; ++qt)
          sacc[qt][kvt] = __builtin_amdgcn_mfma_f32_16x16x32_bf16(
              kf[kvt], qf[qt][kc], sacc[qt][kvt], 0, 0, 0);
    }

    // per k-block kvt: p = exp2(s) -> pkrtz -> A-frag; V B-frag b64; PV MFMA
#pragma unroll
    for (int kvt = 0; kvt < 4; ++kvt) {
      half4 pfr[2];
#pragma unroll
      for (int qt = 0; qt < 2; ++qt) {
        float p0 = EXP2F(sacc[qt][kvt][0]);
        float p1 = EXP2F(sacc[qt][kvt][1]);
        float p2 = EXP2F(sacc[qt][kvt][2]);
        float p3 = EXP2F(sacc[qt][kvt][3]);
        lsum[qt] += (p0 + p1) + (p2 + p3);
        uint2 w;
        w.x = pkh(p0, p1);
        w.y = pkh(p2, p3);
        pfr[qt] = __builtin_bit_cast(half4, w);
      }
      // V B-frag: k = kv = kvt*16 + quad*4 + j, n = d = nt*16 + l16;
      // Vs row d stored with chunk-of-8 swizzle keyed on d&7 (= fsw).
      const int vcol = (((kvt * 2 + (quad >> 1)) ^ fsw) << 3) + (quad & 1) * 4;
#pragma unroll
      for (int nt = 0; nt < 4; ++nt) {
        uint2 vr = *(const uint2*)&Vst[(nt * 16 + l16) * 64 + vcol];
        half4 vfr = __builtin_bit_cast(half4, vr);
#pragma unroll
        for (int qt = 0; qt < 2; ++qt)
          oacc[qt][nt] = __builtin_amdgcn_mfma_f32_16x16x16f16(
              pfr[qt], vfr, oacc[qt][nt], 0, 0, 0);
      }
    }
    // no trailing barrier: next iteration's leading barrier covers reuse.
  }

  // final l reduction: lane has partial for q = qt*16+l16 over its quad's kv
#pragma unroll
  for (int qt = 0; qt < 2; ++qt) {
    float v = lsum[qt];
    v += __shfl_xor(v, 16, 64);
    v += __shfl_xor(v, 32, 64);
    if (quad == 0) Ls[wave][qt * 16 + l16] = v;
  }
  __asm__ volatile("s_waitcnt lgkmcnt(0)" ::: "memory");
  __builtin_amdgcn_wave_barrier();

  const int b = bh >> 4, h = bh & 15;
#pragma unroll
  for (int qt = 0; qt < 2; ++qt) {
    float4 lr = *(const float4*)&Ls[wave][qt * 16 + quad * 4];
    float inv0 = 1.f / lr.x, inv1 = 1.f / lr.y, inv2 = 1.f / lr.z, inv3 = 1.f / lr.w;
#pragma unroll
    for (int nt = 0; nt < 4; ++nt) {
      int d = nt * 16 + l16;
      int qbase = q0 + wave * 32 + qt * 16 + quad * 4;
      size_t obase = ((size_t)(b * 2048 + qbase)) * 1024 + h * 64 + d;
      ob[obase]        = f2bf(oacc[qt][nt][0] * inv0);
      ob[obase + 1024] = f2bf(oacc[qt][nt][1] * inv1);
      ob[obase + 2048] = f2bf(oacc[qt][nt][2] * inv2);
      ob[obase + 3072] = f2bf(oacc[qt][nt][3] * inv3);
    }
  }
}

// ----------------------------- launch --------------------------------------

extern "C" void kernel_launch(void* const* d_in, const int* in_sizes, int n_in,
                              void* d_out, int out_size, void* d_ws, size_t ws_size,
                              hipStream_t stream) {
  const float* x      = (const float*)d_in[0];
  const float* w_qkv  = (const float*)d_in[1];
  const float* b_qkv  = (const float*)d_in[2];
  const float* w_proj = (const float*)d_in[3];
  const float* b_proj = (const float*)d_in[4];
  float* out = (float*)d_out;

  short* xs     = (short*)d_ws;                     // [8192,1024]
  short* wqkvT  = xs + (size_t)8192 * 1024;         // [3072,1024]
  short* wprojT = wqkvT + (size_t)3072 * 1024;      // [1024,1024]
  short* qb     = wprojT + (size_t)1024 * 1024;     // [64,2048,64]
  short* kb     = qb + (size_t)64 * 2048 * 64;      // [64,2048,64]
  short* vtb    = kb + (size_t)64 * 2048 * 64;      // [64,64,2048] f16
  short* aob    = vtb + (size_t)64 * 2048 * 64;     // [8192,1024]

  convert_kernel<<<dim3(4096), 256, 0, stream>>>(x, xs);
  wtrans_kernel<<<dim3(96, 32), dim3(32, 8), 0, stream>>>(w_qkv, wqkvT, 1024, 3072);
  wtrans_kernel<<<dim3(32, 32), dim3(32, 8), 0, stream>>>(w_proj, wprojT, 1024, 1024);

  gemm_kernel<0><<<dim3(24, 64), 256, 0, stream>>>(xs, wqkvT, b_qkv, 3072,
                                                   qb, kb, vtb, nullptr);
  attn_kernel<<<dim3(16, 64), 256, 0, stream>>>(qb, kb, vtb, aob);
  gemm_kernel<1><<<dim3(8, 64), 256, 0, stream>>>(aob, wprojT, b_proj, 1024,
                                                  nullptr, nullptr, nullptr, out);
}